// Round 5
// baseline (398.517 us; speedup 1.0000x reference)
//
#include <hip/hip_runtime.h>

// Problem constants (from setup_inputs): B=16, C_img=3, H=448, W=1024.
#define BB 16
#define HH 448
#define WW 1024
constexpr int HW    = HH * WW;            // 458752
constexpr int NBLK  = BB * HH;            // 7168 blocks, one per (b, row)
constexpr int NTHR  = 256;
constexpr long long TOTAL = (long long)BB * HW;

// Evidence R0-R4: per-wave load serialization at ~550cy avg latency explains
// wave lifetime (116 loads x 550 = 64K cy = measured 62K). R4's source-level
// batching was DEFEATED by the compiler (VGPR=48 proves re-fusion of
// load+use). This version pins the schedule with sched_barrier(0):
//   per chunk: [issue 12 gathers + 3 img1] | fence | [issue next flow x14]
//              | fence | [VALU: epe/smooth] | [consume gathers, vmcnt(14)]
// so gather latency hides under VALU and flow latency hides under the whole
// next chunk. Lane<->x mapping kept (R1/R2: stride-16B gathers = 64-line
// instructions = 1.5x slower).

struct FlowRaw {
    float m0, m1, l0, l1, e0, e1;        // self row
    float dm0, dm1, dl0, dl1, de0, de1;  // down row
    float t0, t1;                        // target
};

__global__ __launch_bounds__(NTHR) void elbo_main(
    const float* __restrict__ mean, const float* __restrict__ lvar,
    const float* __restrict__ img1, const float* __restrict__ img2,
    const float* __restrict__ target, const float* __restrict__ eps,
    float2* __restrict__ partials)
{
    // XCD-chunked bijective swizzle (7168 % 8 == 0).
    constexpr int NXCD = 8, CPX = NBLK / NXCD;
    const int wg = (blockIdx.x % NXCD) * CPX + blockIdx.x / NXCD;

    const int b = wg / HH;
    const int y = wg - b * HH;
    const int t = threadIdx.x;

    const int fbase = b * 2 * HW + y * WW;   // flow ch-0 offset of row start
    const int ibase = b * 3 * HW;
    const bool have_dn = (y + 1) < HH;       // false only for row 447

    const float* __restrict__ p2c0 = img2 + ibase;
    const float* __restrict__ p2c1 = img2 + ibase + HW;
    const float* __restrict__ p2c2 = img2 + ibase + 2 * HW;

    float se = 0.f;   // elbo partial (data + smooth - 0.5*sum(logvar))
    float sp = 0.f;   // epe partial

    auto load_raw = [&](int k, FlowRaw& r) {
        const int o = fbase + (k << 8) + t;
        r.m0 = mean[o];   r.m1 = mean[o + HW];
        r.l0 = lvar[o];   r.l1 = lvar[o + HW];
        r.e0 = eps[o];    r.e1 = eps[o + HW];
        r.t0 = target[o]; r.t1 = target[o + HW];
        if (have_dn) {   // y=447 down-row would run off the allocation
            r.dm0 = mean[o + WW]; r.dm1 = mean[o + WW + HW];
            r.dl0 = lvar[o + WW]; r.dl1 = lvar[o + WW + HW];
            r.de0 = eps[o + WW];  r.de1 = eps[o + WW + HW];
        } else {
            r.dm0 = r.dm1 = r.dl0 = r.dl1 = r.de0 = r.de1 = 0.f;
        }
    };

    FlowRaw cur, nxt;
    load_raw(0, cur);

    #pragma unroll
    for (int k = 0; k < 4; ++k) {
        const int x = (k << 8) + t;
        const int o = fbase + x;

        // ---- flows for this chunk (cur loads have had a full chunk to land) ----
        const float u = cur.m0 + __expf(0.5f * cur.l0) * cur.e0;
        const float v = cur.m1 + __expf(0.5f * cur.l1) * cur.e1;
        float un = 0.f, vn = 0.f;
        if (have_dn) {
            un = cur.dm0 + __expf(0.5f * cur.dl0) * cur.de0;
            vn = cur.dm1 + __expf(0.5f * cur.dl1) * cur.de1;
        }

        // ---- gather addresses ----
        const float xs = (float)x + u;
        const float ys = (float)y + v;
        const float x0f = floorf(xs), y0f = floorf(ys);
        const float wx = xs - x0f,    wy = ys - y0f;
        int x0 = (int)x0f; x0 = min(max(x0, 0), WW - 1);
        const int x1 = min(x0 + 1, WW - 1);
        int yy0 = (int)y0f; yy0 = min(max(yy0, 0), HH - 1);
        const int yy1 = min(yy0 + 1, HH - 1);
        const int i00 = yy0 * WW + x0, i01 = yy0 * WW + x1;
        const int i10 = yy1 * WW + x0, i11 = yy1 * WW + x1;
        const int ro  = y * WW + x;

        // ---- issue ALL 15 chunk loads (12 gathers + 3 img1) ----
        const float a00 = p2c0[i00], a01 = p2c0[i01], a10 = p2c0[i10], a11 = p2c0[i11];
        const float b00 = p2c1[i00], b01 = p2c1[i01], b10 = p2c1[i10], b11 = p2c1[i11];
        const float c00 = p2c2[i00], c01 = p2c2[i01], c10 = p2c2[i10], c11 = p2c2[i11];
        const float i1a = img1[ibase + ro];
        const float i1b = img1[ibase + HW + ro];
        const float i1c = img1[ibase + 2 * HW + ro];
        __builtin_amdgcn_sched_barrier(0);   // pin: gathers stay issued here

        // ---- issue next chunk's 14 flow loads (in flight across consume) ----
        if (k < 3) load_raw(k + 1, nxt);
        __builtin_amdgcn_sched_barrier(0);   // pin: flow stays above VALU

        // ---- VALU work needing no gathers (hides gather latency) ----
        {
            const float du = cur.m0 - cur.t0, dv = cur.m1 - cur.t1;
            sp += sqrtf(du * du + dv * dv);
        }
        se -= 0.5f * (cur.l0 + cur.l1);

        float uR = __shfl_down(u, 1);
        float vR = __shfl_down(v, 1);
        if (((t & 63) == 63) && (x + 1 < WW)) {   // wave-boundary fallback
            const int o1 = o + 1;
            uR = mean[o1]      + __expf(0.5f * lvar[o1])      * eps[o1];
            vR = mean[o1 + HW] + __expf(0.5f * lvar[o1 + HW]) * eps[o1 + HW];
        }
        float dx2 = 0.f, dy2 = 0.f;
        if (x < WW - 1) { const float a = uR - u, c = vR - v; dx2 = a * a + c * c; }
        if (have_dn)    { const float a = un - u, c = vn - v; dy2 = a * a + c * c; }
        se += sqrtf(dx2 + dy2 + 1e-5f);

        // ---- consume gathers (auto-waitcnt ~vmcnt(14): flow stays in flight) ----
        float A = 0.f;
        {
            const float top = a00 + wx * (a01 - a00);
            const float bot = a10 + wx * (a11 - a10);
            const float w   = top + wy * (bot - top);
            const float d   = i1a - w;  A += d * d;
        }
        {
            const float top = b00 + wx * (b01 - b00);
            const float bot = b10 + wx * (b11 - b10);
            const float w   = top + wy * (bot - top);
            const float d   = i1b - w;  A += d * d;
        }
        {
            const float top = c00 + wx * (c01 - c00);
            const float bot = c10 + wx * (c11 - c10);
            const float w   = top + wy * (bot - top);
            const float d   = i1c - w;  A += d * d;
        }
        se += sqrtf(A + 1e-5f);

        if (k < 3) cur = nxt;
    }

    // ---- block reduction: wave shuffle then LDS across 4 waves ----
    #pragma unroll
    for (int off = 32; off > 0; off >>= 1) {
        se += __shfl_down(se, off);
        sp += __shfl_down(sp, off);
    }
    __shared__ float s_e[NTHR / 64], s_p[NTHR / 64];
    const int lane = threadIdx.x & 63;
    const int wid  = threadIdx.x >> 6;
    if (lane == 0) { s_e[wid] = se; s_p[wid] = sp; }
    __syncthreads();
    if (threadIdx.x == 0) {
        float te = 0.0f, tp = 0.0f;
        #pragma unroll
        for (int i = 0; i < NTHR / 64; ++i) { te += s_e[i]; tp += s_p[i]; }
        partials[blockIdx.x] = make_float2(te, tp);
    }
}

// 16-wave final reduction: each thread 7 independent loads, one latency
// exposure (R4 version, kept).
__global__ __launch_bounds__(1024) void elbo_final(
    const float2* __restrict__ partials, float* __restrict__ out)
{
    constexpr int PER = NBLK / 1024;     // 7
    float2 v[PER];
    #pragma unroll
    for (int j = 0; j < PER; ++j) v[j] = partials[threadIdx.x + j * 1024];

    double se = 0.0, sp = 0.0;
    #pragma unroll
    for (int j = 0; j < PER; ++j) { se += (double)v[j].x; sp += (double)v[j].y; }

    #pragma unroll
    for (int off = 32; off > 0; off >>= 1) {
        se += __shfl_down(se, off);
        sp += __shfl_down(sp, off);
    }
    __shared__ double s_e[16], s_p[16];
    const int lane = threadIdx.x & 63;
    const int wid  = threadIdx.x >> 6;
    if (lane == 0) { s_e[wid] = se; s_p[wid] = sp; }
    __syncthreads();
    if (threadIdx.x == 0) {
        double te = 0.0, tp = 0.0;
        #pragma unroll
        for (int i = 0; i < 16; ++i) { te += s_e[i]; tp += s_p[i]; }
        out[0] = (float)(te / (double)BB);
        out[1] = (float)(tp / (double)TOTAL);
    }
}

extern "C" void kernel_launch(void* const* d_in, const int* in_sizes, int n_in,
                              void* d_out, int out_size, void* d_ws, size_t ws_size,
                              hipStream_t stream) {
    const float* mean   = (const float*)d_in[0];
    const float* logvar = (const float*)d_in[1];
    const float* img1   = (const float*)d_in[2];
    const float* img2   = (const float*)d_in[3];
    const float* target = (const float*)d_in[4];
    const float* eps    = (const float*)d_in[5];
    float* out = (float*)d_out;
    float2* partials = (float2*)d_ws;   // NBLK * 8 bytes = 56 KiB

    elbo_main<<<NBLK, NTHR, 0, stream>>>(mean, logvar, img1, img2, target, eps, partials);
    elbo_final<<<1, 1024, 0, stream>>>(partials, out);
}